// Round 10
// baseline (534.678 us; speedup 1.0000x reference)
//
#include <hip/hip_runtime.h>
#include <hip/hip_bf16.h>
#include <math.h>

typedef unsigned short ushort;
typedef unsigned int uint;

// Sizes (fixed by the reference problem)
#define NV 200     // N nodes
#define DEG 199
#define HID 96
#define KG 20      // groups / one-hot width
#define MG 10      // group size
#define AJR 30
#define NH 4
#define HD 118     // HID + 2 + K
#define DM 472     // NH*HD
#define NN 40000   // N*N
#define NT 20100   // N*(N+1)/2 unique (i<=j) pairs: S[(i,j)] == S[(j,i)]
#define NTP 20160  // NT rounded up to 64

// Workspace layout (float units).
#define WS_BASE   0
#define WS_H1     19200
#define WS_H2     38400
#define WS_HFULL  57600
#define WS_KHF    194952   // khfT [DM][NV] = 94400 floats (transposed!)
#define WS_VHF    289352
#define WS_B1     383752   // after k_SC: reused for C (softmax row consts)
#define WS_B2     478152
#define WS_SC1    572552
#define WS_SC2    732552
#define WS_ZT     1315464  // ZT bf16: 512*896 ushorts = 229,376 floats

// Output layout (floats)
#define OFF_H   18880000
#define OFF_HF  18899200
#define OFF_Q   18922800

typedef __attribute__((ext_vector_type(8))) short short8v;
typedef __attribute__((ext_vector_type(4))) float float4v;

__device__ __forceinline__ ushort f2bf(float f) {
  uint u = __float_as_uint(f);
  uint r = (u + 0x7fffu + ((u >> 16) & 1u)) >> 16;  // RNE
  return (ushort)r;
}
__device__ __forceinline__ uint packbf(float a, float b) {
  __hip_bfloat162 h2 = __float22bfloat162_rn(make_float2(a, b));
  union { __hip_bfloat162 h; uint u; } c;
  c.h = h2;
  return c.u;
}

// Packed upper-triangle index p (0..NT-1) -> (i,j), i<=j.
__device__ __forceinline__ int triOff(int i) {
  return i * 200 - ((i * (i - 1)) >> 1);
}
__device__ __forceinline__ void p2ij(int p, int& io, int& jo) {
  float s = sqrtf((float)(160801 - 8 * p));   // (2N+1)^2 - 8p
  int i = (int)((401.0f - s) * 0.5f);
  if (i < 0) i = 0;
  if (i > 199) i = 199;
  while (i > 0 && triOff(i) > p) --i;
  while (i < 199 && triOff(i + 1) <= p) ++i;
  io = i;
  jo = i + (p - triOff(i));
}

// ---------------------------------------------------------------------------
// A: iteration-invariant part of the GCN update
// ---------------------------------------------------------------------------
__global__ __launch_bounds__(256) void k_base(
    const float* __restrict__ x, const float* __restrict__ dmat,
    const float* __restrict__ label,
    const float* __restrict__ l0w, const float* __restrict__ l0b,
    const float* __restrict__ l1w, const float* __restrict__ l1b,
    const float* __restrict__ l2b, const float* __restrict__ l3b,
    const float* __restrict__ l4w, const float* __restrict__ l4b,
    const float* __restrict__ l5w, const float* __restrict__ l5b,
    float* __restrict__ base) {
  int i = blockIdx.x; int t = threadIdx.x;
  int g = i / MG;
  __shared__ float sv[256];
  __shared__ float sn2[9];
  float v = -1.0f;
  if (t < DEG) {
    int u = (t < i) ? t : t + 1;
    if (u / MG != g) v = dmat[i * DEG + t];
  }
  sv[t] = v;
  __syncthreads();
  for (int k2 = 2; k2 <= 256; k2 <<= 1) {
    for (int jj = k2 >> 1; jj > 0; jj >>= 1) {
      int ixj = t ^ jj;
      if (ixj > t) {
        float a = sv[t], b = sv[ixj];
        bool sw = ((t & k2) == 0) ? (a < b) : (a > b);
        if (sw) { sv[t] = b; sv[ixj] = a; }
      }
      __syncthreads();
    }
  }
  if (t == 0) {
    float tmp[9];
    for (int q = 0; q < 9; q++) tmp[q] = dmat[i * DEG + MG * g + q];
    for (int a2 = 1; a2 < 9; a2++) {
      float key = tmp[a2]; int b2 = a2 - 1;
      while (b2 >= 0 && tmp[b2] < key) { tmp[b2 + 1] = tmp[b2]; b2--; }
      tmp[b2 + 1] = key;
    }
    for (int q = 0; q < 9; q++) sn2[q] = tmp[q];
  }
  __syncthreads();
  if (t < HID) {
    float acc = l0b[t] + l1b[t] + l2b[t] + l3b[t] + l4b[t] + l5b[t];
    acc += x[i * 2 + 0] * l0w[t] + x[i * 2 + 1] * l0w[HID + t];
    for (int k = 0; k < KG; k++) acc += label[i * KG + k] * l1w[k * HID + t];
    for (int q = 0; q < AJR; q++) acc += sv[q] * l4w[q * HID + t];
    for (int q = 0; q < 9; q++) acc += sn2[q] * l5w[q * HID + t];
    base[i * HID + t] = acc;
  }
}

// ---------------------------------------------------------------------------
// B (v11): one GCN step, serial length quartered. 512 threads:
//   t<384: 4 groups x 96 threads, n1 partials over j-quarters;
//   384<=t<416: n2 (3 dd each). Then dd-matmul split 4 ways (24 dd each).
// ---------------------------------------------------------------------------
__global__ __launch_bounds__(512) void k_gcn4(
    const float* __restrict__ hin, const float* __restrict__ base,
    const float* __restrict__ w, const float* __restrict__ l2w,
    const float* __restrict__ l3w, float* __restrict__ hout) {
  int i = blockIdx.x; int t = threadIdx.x;
  int g = i / MG;
  __shared__ float pJ[4][HID], wJ[4][HID];
  __shared__ float n1s[HID], n2s[HID];
  __shared__ float m[4][HID];
  if (t < 384) {
    int q = t / HID;
    int c = t - q * HID;
    int j0 = q * 50, j1 = (q == 3) ? DEG : (j0 + 50);
    float acc = 0.f, ws = 0.f;
    for (int j = j0; j < j1; j++) {
      int u = (j < i) ? j : j + 1;
      if (u / MG != g) {
        float wj = w[i * DEG + j];
        acc += wj * hin[u * HID + c];
        ws += wj;
      }
    }
    pJ[q][c] = acc; wJ[q][c] = ws;
  } else if (t < 416) {
#pragma unroll
    for (int q2 = 0; q2 < 3; q2++) {
      int dd = (t - 384) * 3 + q2;
      float acc = 0.f, ws = 0.f;
      for (int u = MG * g; u < MG * g + MG; u++) {
        if (u == i) continue;
        int j = (u < i) ? u : u - 1;
        float wj = w[i * DEG + j];
        acc += wj * hin[u * HID + dd];
        ws += wj;
      }
      n2s[dd] = acc / ws;
    }
  }
  __syncthreads();
  if (t < HID)
    n1s[t] = (pJ[0][t] + pJ[1][t] + pJ[2][t] + pJ[3][t]) /
             (wJ[0][t] + wJ[1][t] + wJ[2][t] + wJ[3][t]);
  __syncthreads();
  if (t < 384) {
    int q = t / HID, c = t - q * HID;
    int d0 = q * 24;
    float acc = 0.f;
    for (int dd = d0; dd < d0 + 24; dd++)
      acc += n1s[dd] * l2w[dd * HID + c] + n2s[dd] * l3w[dd * HID + c];
    m[q][c] = acc;
  }
  __syncthreads();
  if (t < HID)
    hout[i * HID + t] =
        fmaxf(base[i * HID + t] + m[0][t] + m[1][t] + m[2][t] + m[3][t], 0.f);
}

// ---------------------------------------------------------------------------
// C1: h_full assembly (+ h, h_full outputs)
// ---------------------------------------------------------------------------
__global__ __launch_bounds__(128) void k_hfull(
    const float* __restrict__ h, const float* __restrict__ x,
    const float* __restrict__ label, const int* __restrict__ remain_step,
    float* __restrict__ hfull, float* __restrict__ out_h,
    float* __restrict__ out_hf) {
  int i = blockIdx.x; int t = threadIdx.x;
  if (t < HD) {
    float v;
    if (t < HID) {
      int p = *remain_step;
      int t2 = t & ~1;
      float div = expf(-(float)t2 * (logf(10000.f) / (float)HID));
      float ang = (float)p * div;
      float pe = (t & 1) ? cosf(ang) : sinf(ang);
      float hv = h[i * HID + t];
      out_h[i * HID + t] = hv;
      v = hv + pe;
    } else if (t < HID + 2) {
      v = x[i * 2 + (t - HID)];
    } else {
      v = label[i * KG + (t - HID - 2)];
    }
    hfull[i * HD + t] = v;
    out_hf[i * HD + t] = v;
  }
}

// ---------------------------------------------------------------------------
// D (v11): fused k_wsum + k_kv + k_B + k_gmean (gr computed inline).
// Grid (NV, 2): column halves.
// ---------------------------------------------------------------------------
__global__ __launch_bounds__(256) void k_kvB(
    const float* __restrict__ hfull,
    const float* __restrict__ w0, const float* __restrict__ b0v,
    const float* __restrict__ w1, const float* __restrict__ b1v,
    float* __restrict__ khfT, float* __restrict__ vhf,
    float* __restrict__ B1, float* __restrict__ B2) {
  int i = blockIdx.x; int t = threadIdx.x; int g = i / MG;
  int half = blockIdx.y;
  __shared__ float hr[HD], gr[HD];
  if (t < HD) {
    hr[t] = hfull[i * HD + t];
    float s = 0.f;
    for (int q = 0; q < MG; q++) s += hfull[(g * MG + q) * HD + t];
    gr[t] = s * 0.1f;
  }
  __syncthreads();
  for (int c = half * 236 + t; c < 236 + half * 236; c += 256) {
    const float* w0c = w0 + c;
    const float* w1c = w1 + c;
    float d0 = 0.f, d1 = 0.f, d2 = 0.f, d3 = 0.f;
    float g2 = 0.f, g3 = 0.f;
    float e0 = 0.f, e1 = 0.f, e2 = 0.f, e3 = 0.f;
    for (int dd = 0; dd < HD; dd++) {
      float hv = hr[dd], gv = gr[dd];
      float a0 = w0c[dd * DM];
      float a1 = w0c[(HD + dd) * DM];
      float a2 = w0c[(2 * HD + dd) * DM];
      float a3 = w0c[(3 * HD + dd) * DM];
      d0 += hv * a0; d1 += hv * a1; d2 += hv * a2; d3 += hv * a3;
      g2 += gv * a2; g3 += gv * a3;
      e0 += hv * w1c[dd * DM];
      e1 += hv * w1c[(HD + dd) * DM];
      e2 += hv * w1c[(2 * HD + dd) * DM];
      e3 += hv * w1c[(3 * HD + dd) * DM];
    }
    float b0c = b0v[c];
    khfT[c * NV + i] = b0c + d0 + d1 + d2 + d3;
    vhf[i * DM + c] = b1v[c] + e0 + e1 + e2 + e3;
    B1[i * DM + c] = d0 + g2;
    B2[i * DM + c] = b0c + d1 + g3;
  }
}

// D4 (v11): score components; grid (NV, 4) -- p-range quarters.
__global__ __launch_bounds__(256) void k_SC(
    const float* __restrict__ B1, const float* __restrict__ B2,
    const float* __restrict__ khfT, float* __restrict__ SC1,
    float* __restrict__ SC2) {
  int i = blockIdx.x; int t = threadIdx.x;
  int qtr = blockIdx.y;
  const float scl = 1.4426950408889634f / sqrtf((float)HD);
  __shared__ float b1r[DM], b2r[DM];
  for (int c = t; c < DM; c += 256) { b1r[c] = B1[i * DM + c]; b2r[c] = B2[i * DM + c]; }
  __syncthreads();
  for (int p = qtr * 200 + t; p < qtr * 200 + 200; p += 256) {
    int h = p / NV, k = p - h * NV;
    float s1a = 0.f, s2a = 0.f;
    const float* kc = khfT + (size_t)h * HD * NV + k;
    const float* b1h = b1r + h * HD;
    const float* b2h = b2r + h * HD;
    for (int dd = 0; dd < HD; dd++) {
      float kv = kc[dd * NV];
      s1a += b1h[dd] * kv;
      s2a += b2h[dd] * kv;
    }
    SC1[h * NN + i * NV + k] = s1a * scl;
    SC2[h * NN + i * NV + k] = s2a * scl;
  }
}

// D5 (v11): softmax row constants; grid (NV, NH*2) -- j-range halves.
__global__ __launch_bounds__(256) void k_ml(
    const float* __restrict__ SC1, const float* __restrict__ SC2,
    float* __restrict__ C) {
  int i = blockIdx.x;
  int h = blockIdx.y >> 1, jh = blockIdx.y & 1;
  int t = threadIdx.x;
  __shared__ float s1s[224];
  for (int k = t; k < 224; k += 256)
    s1s[k] = (k < NV) ? SC1[h * NN + i * NV + k] : -1e30f;
  __syncthreads();
  int l = t & 31;
  int g = t >> 5;
  const float* s2b = SC2 + h * NN;
  int it0 = jh ? 13 : 0, it1 = jh ? 25 : 13;
  for (int it = it0; it < it1; ++it) {
    int j = it * 8 + g;
    const float* row = s2b + j * NV;
    float v[7];
#pragma unroll
    for (int e = 0; e < 7; ++e) {
      int k = l + 32 * e;
      v[e] = (k < NV) ? (s1s[k] + row[k]) : -1e30f;
    }
    float m = v[0];
#pragma unroll
    for (int e = 1; e < 7; ++e) m = fmaxf(m, v[e]);
#pragma unroll
    for (int off = 16; off > 0; off >>= 1) m = fmaxf(m, __shfl_xor(m, off, 32));
    float s = 0.f;
#pragma unroll
    for (int e = 0; e < 7; ++e) s += exp2f(v[e] - m);
#pragma unroll
    for (int off = 16; off > 0; off >>= 1) s += __shfl_xor(s, off, 32);
    if (l == 0) C[h * NN + i * NV + j] = m + log2f(s);
  }
}

// ---------------------------------------------------------------------------
// E: merged k_Z + k_ZT. Writes bf16 directly into transposed zero-padded
// ZT[c][h*224+k] (512x896). Grid (224, NH).
// ---------------------------------------------------------------------------
__global__ __launch_bounds__(256) void k_ZZT(
    const float* __restrict__ vhf, const float* __restrict__ w3,
    ushort* __restrict__ ZT) {
  int k = blockIdx.x, h = blockIdx.y;
  int t = threadIdx.x;
  __shared__ float vr[HD];
  if (k < NV && t < HD) vr[t] = vhf[k * DM + h * HD + t];
  __syncthreads();
  for (int c = t; c < 512; c += 256) {
    float a = 0.f;
    if (k < NV && c < DM) {
      for (int d = 0; d < HD; ++d) a += vr[d] * w3[(h * HD + d) * DM + c];
    }
    ZT[(size_t)c * 896 + h * 224 + k] = f2bf(a);
  }
}

// ---------------------------------------------------------------------------
// F (v11): fused attention+output GEMM over UNIQUE row pairs.
// 64 packed rows x 256 cols, grid (2, 315): halves the exp2 redundancy
// (4x -> 2x) vs the (4,315) 128-col variant, same 8 exp2-pairs/step now
// feeding 16 MFMA. v5's proven in-register A-gen + 2-barrier step; v7's
// 256-col staging. 630 blocks ~ the ~2.6 blocks/CU residency v5 actually
// achieved, so occupancy is preserved while VALU work halves.
// ---------------------------------------------------------------------------
__global__ __launch_bounds__(256) void k_sfusedT3(
    const float* __restrict__ SC1, const float* __restrict__ SC2,
    const float* __restrict__ C, const ushort* __restrict__ ZT,
    const float* __restrict__ b3, float* __restrict__ outS) {
  int t = threadIdx.x;
  int c0 = blockIdx.x * 256, p0 = blockIdx.y * 64;
  int lane = t & 63, wm = t >> 6;
  int frow = lane & 15, quad = lane >> 4;
  __shared__ __align__(16) ushort Bs[256 * 40];
  int p = p0 + wm * 16 + frow;
  bool bval = (p < NT);
  int iA = 0, jA = 0;
  if (bval) p2ij(p, iA, jA);
  int iN = iA * NV, jN = jA * NV;
  float4v acc[16];
#pragma unroll
  for (int n = 0; n < 16; ++n) acc[n] = (float4v)(0.f);

  for (int h = 0; h < NH; ++h) {
    int hb = h * NN;
    const float* s1h = SC1 + hb;
    const float* s2h = SC2 + hb;
    float ci = bval ? C[hb + iN + jA] : 0.f;
    float cj = bval ? C[hb + jN + iA] : 0.f;
    for (int ks = 0; ks < 7; ++ks) {
      int kb = ks * 32 + quad * 8;
      bool kvalid = (kb + 7 < NV);
      // --- issue B-tile loads early (hide under exp2) ---
      uint4 bq[4];
#pragma unroll
      for (int qq = 0; qq < 4; ++qq) {
        int li = qq * 256 + t;           // 0..1023
        int c = li >> 2;                 // 0..255
        int ko = (li & 3) * 8;           // 0,8,16,24 ushorts
        bq[qq] = *(const uint4*)(ZT + (size_t)(c0 + c) * 896 + h * 224 +
                                 ks * 32 + ko);
      }
      // --- generate A fragment in-register (v5's proven pattern) ---
      union { uint4 q; short8v v; } af;
      if (bval && kvalid) {
        const float* q1i = s1h + iN + kb;
        const float* q2i = s2h + iN + kb;
        const float* q1j = s1h + jN + kb;
        const float* q2j = s2h + jN + kb;
        float4 a0 = *(const float4*)q1i,   a0b = *(const float4*)(q1i + 4);
        float4 b0 = *(const float4*)q2j,   b0b = *(const float4*)(q2j + 4);
        float4 d0 = *(const float4*)q1j,   d0b = *(const float4*)(q1j + 4);
        float4 e0 = *(const float4*)q2i,   e0b = *(const float4*)(q2i + 4);
        float p0_ = exp2f(a0.x + b0.x - ci) + exp2f(d0.x + e0.x - cj);
        float p1_ = exp2f(a0.y + b0.y - ci) + exp2f(d0.y + e0.y - cj);
        float p2_ = exp2f(a0.z + b0.z - ci) + exp2f(d0.z + e0.z - cj);
        float p3_ = exp2f(a0.w + b0.w - ci) + exp2f(d0.w + e0.w - cj);
        float p4_ = exp2f(a0b.x + b0b.x - ci) + exp2f(d0b.x + e0b.x - cj);
        float p5_ = exp2f(a0b.y + b0b.y - ci) + exp2f(d0b.y + e0b.y - cj);
        float p6_ = exp2f(a0b.z + b0b.z - ci) + exp2f(d0b.z + e0b.z - cj);
        float p7_ = exp2f(a0b.w + b0b.w - ci) + exp2f(d0b.w + e0b.w - cj);
        af.q.x = packbf(p0_, p1_);
        af.q.y = packbf(p2_, p3_);
        af.q.z = packbf(p4_, p5_);
        af.q.w = packbf(p6_, p7_);
      } else {
        af.q = make_uint4(0, 0, 0, 0);
      }
      __syncthreads();  // previous step's MFMA reads of Bs complete
#pragma unroll
      for (int qq = 0; qq < 4; ++qq) {
        int li = qq * 256 + t;
        int c = li >> 2;
        int ko = (li & 3) * 8;
        *(uint4*)&Bs[c * 40 + ko] = bq[qq];
      }
      __syncthreads();
      // --- MFMA: 16 column fragments (n*16 >= 216 dead only when c0=256) ---
#pragma unroll
      for (int n = 0; n < 16; ++n) {
        if (c0 + n * 16 < DM) {          // wave-uniform guard
          short8v bf = *(const short8v*)&Bs[(n * 16 + frow) * 40 + quad * 8];
          acc[n] = __builtin_amdgcn_mfma_f32_16x16x32_bf16(af.v, bf, acc[n],
                                                           0, 0, 0);
        }
      }
    }
  }
  // epilogue: C/D layout col=lane&15, row=quad*4+reg; mirror to (j,i).
  int ie[4], je[4];
#pragma unroll
  for (int r2 = 0; r2 < 4; ++r2) {
    int pe = p0 + wm * 16 + quad * 4 + r2;
    if (pe < NT) {
      p2ij(pe, ie[r2], je[r2]);
    } else {
      ie[r2] = -1; je[r2] = 0;
    }
  }
#pragma unroll
  for (int n = 0; n < 16; ++n) {
    int c = c0 + n * 16 + frow;
    if (c >= DM) continue;
    float bb = 2.0f * b3[c];
#pragma unroll
    for (int r2 = 0; r2 < 4; ++r2) {
      int ii = ie[r2];
      if (ii < 0) continue;
      int jj = je[r2];
      float v = acc[n][r2] + bb;
      outS[(size_t)(ii * NV + jj) * DM + c] = v;
      if (ii != jj) outS[(size_t)(jj * NV + ii) * DM + c] = v;
    }
  }
}

// ---------------------------------------------------------------------------
// G: Q_sa = relu(S@v1+b1)@v2 + b2 over unique rows; 32 rows/block,
// 59-col chunks, conflict-free padded LDS. Mirror write.
// ---------------------------------------------------------------------------
__global__ __launch_bounds__(256) void k_qsaT2(
    const float* __restrict__ S, const float* __restrict__ v1w,
    const float* __restrict__ v1b, const float* __restrict__ v2w,
    const float* __restrict__ v2b, float* __restrict__ outQ) {
  __shared__ float Ss[32][61];
  __shared__ float V1s[59][48];
  __shared__ float Ts[32][49];
  __shared__ int rowI[32], rowJ[32], rowOfs[32];
  int t = threadIdx.x;
  int p0b = blockIdx.x * 32;
  if (t < 32) {
    int p = p0b + t;
    if (p < NT) {
      int ii, jj; p2ij(p, ii, jj);
      rowI[t] = ii; rowJ[t] = jj; rowOfs[t] = ii * NV + jj;
    } else {
      rowI[t] = -1; rowJ[t] = 0; rowOfs[t] = 0;
    }
  }
  int ty2 = (t >> 4) * 2;     // rows ty2, ty2+1
  int tx3 = (t & 15) * 3;     // q outputs tx3..tx3+2
  float a00 = 0.f, a01 = 0.f, a02 = 0.f, a10 = 0.f, a11 = 0.f, a12 = 0.f;
  for (int k0 = 0; k0 < DM; k0 += 59) {
    __syncthreads();
    for (int e = t; e < 32 * 59; e += 256) {
      int r = e / 59, cc = e - r * 59;
      Ss[r][cc] = S[(size_t)rowOfs[r] * DM + k0 + cc];
    }
    for (int e = t; e < 59 * 48; e += 256) {
      int kk = e / 48, cc = e - kk * 48;
      V1s[kk][cc] = v1w[(size_t)(k0 + kk) * 48 + cc];
    }
    __syncthreads();
    for (int kk = 0; kk < 59; ++kk) {
      float s0 = Ss[ty2][kk], s1 = Ss[ty2 + 1][kk];
      float w0_ = V1s[kk][tx3], w1_ = V1s[kk][tx3 + 1], w2_ = V1s[kk][tx3 + 2];
      a00 += s0 * w0_; a01 += s0 * w1_; a02 += s0 * w2_;
      a10 += s1 * w0_; a11 += s1 * w1_; a12 += s1 * w2_;
    }
  }
  float b0 = v1b[tx3], b1 = v1b[tx3 + 1], b2 = v1b[tx3 + 2];
  Ts[ty2][tx3] = fmaxf(a00 + b0, 0.f);
  Ts[ty2][tx3 + 1] = fmaxf(a01 + b1, 0.f);
  Ts[ty2][tx3 + 2] = fmaxf(a02 + b2, 0.f);
  Ts[ty2 + 1][tx3] = fmaxf(a10 + b0, 0.f);
  Ts[ty2 + 1][tx3 + 1] = fmaxf(a11 + b1, 0.f);
  Ts[ty2 + 1][tx3 + 2] = fmaxf(a12 + b2, 0.f);
  __syncthreads();
  if (t < 32 && rowI[t] >= 0) {
    float q = v2b[0];
    for (int c = 0; c < 48; c++) q += Ts[t][c] * v2w[c];
    int ii = rowI[t], jj = rowJ[t];
    outQ[ii * NV + jj] = q;
    if (ii != jj) outQ[jj * NV + ii] = q;
  }
}

// ---------------------------------------------------------------------------
extern "C" void kernel_launch(void* const* d_in, const int* in_sizes, int n_in,
                              void* d_out, int out_size, void* d_ws,
                              size_t ws_size, hipStream_t stream) {
  const float* x = (const float*)d_in[0];
  const float* label = (const float*)d_in[1];
  const float* h0 = (const float*)d_in[2];
  const float* w = (const float*)d_in[3];
  const float* dmat = (const float*)d_in[4];
  const float* l0w = (const float*)d_in[5];
  const float* l0b = (const float*)d_in[6];
  const float* l1w = (const float*)d_in[7];
  const float* l1b = (const float*)d_in[8];
  const float* l2w = (const float*)d_in[9];
  const float* l2b = (const float*)d_in[10];
  const float* l3w = (const float*)d_in[11];
  const float* l3b = (const float*)d_in[12];
  const float* l4w = (const float*)d_in[13];
  const float* l4b = (const float*)d_in[14];
  const float* l5w = (const float*)d_in[15];
  const float* l5b = (const float*)d_in[16];
  const float* w0 = (const float*)d_in[17];
  const float* b0v = (const float*)d_in[18];
  const float* w1 = (const float*)d_in[19];
  const float* b1v = (const float*)d_in[20];
  const float* w3 = (const float*)d_in[21];
  const float* b3 = (const float*)d_in[22];
  const float* v1w = (const float*)d_in[23];
  const float* v1b = (const float*)d_in[24];
  const float* v2w = (const float*)d_in[25];
  const float* v2b = (const float*)d_in[26];
  const int* remain_step = (const int*)d_in[29];

  float* ws = (float*)d_ws;
  float* base = ws + WS_BASE;
  float* h1 = ws + WS_H1;
  float* h2 = ws + WS_H2;
  float* hfull = ws + WS_HFULL;
  float* khfT = ws + WS_KHF;
  float* vhf = ws + WS_VHF;
  float* B1 = ws + WS_B1;
  float* B2 = ws + WS_B2;
  float* SC1 = ws + WS_SC1;
  float* SC2 = ws + WS_SC2;
  ushort* ZT = (ushort*)(ws + WS_ZT);
  float* C = ws + WS_B1;  // reuses B1/B2 slots after k_SC

  float* outS = (float*)d_out;
  float* outH = outS + OFF_H;
  float* outHF = outS + OFF_HF;
  float* outQ = outS + OFF_Q;

  k_base<<<NV, 256, 0, stream>>>(x, dmat, label, l0w, l0b, l1w, l1b, l2b, l3b,
                                 l4w, l4b, l5w, l5b, base);
  k_gcn4<<<NV, 512, 0, stream>>>(h0, base, w, l2w, l3w, h1);
  k_gcn4<<<NV, 512, 0, stream>>>(h1, base, w, l2w, l3w, h2);
  k_hfull<<<NV, 128, 0, stream>>>(h2, x, label, remain_step, hfull, outH, outHF);
  k_kvB<<<dim3(NV, 2), 256, 0, stream>>>(hfull, w0, b0v, w1, b1v, khfT, vhf,
                                         B1, B2);
  k_ZZT<<<dim3(224, NH), 256, 0, stream>>>(vhf, w3, ZT);
  k_SC<<<dim3(NV, 4), 256, 0, stream>>>(B1, B2, khfT, SC1, SC2);
  k_ml<<<dim3(NV, NH * 2), 256, 0, stream>>>(SC1, SC2, C);
  k_sfusedT3<<<dim3(2, NTP / 64), 256, 0, stream>>>(SC1, SC2, C, ZT, b3, outS);
  k_qsaT2<<<(NT + 31) / 32, 256, 0, stream>>>(outS, v1w, v1b, v2w, v2b, outQ);
}

// Round 11
// 459.473 us; speedup vs baseline: 1.1637x; 1.1637x over previous
//
#include <hip/hip_runtime.h>
#include <hip/hip_bf16.h>
#include <math.h>

typedef unsigned short ushort;
typedef unsigned int uint;

// Sizes (fixed by the reference problem)
#define NV 200     // N nodes
#define DEG 199
#define HID 96
#define KG 20      // groups / one-hot width
#define MG 10      // group size
#define AJR 30
#define NH 4
#define HD 118     // HID + 2 + K
#define DM 472     // NH*HD
#define NN 40000   // N*N
#define NT 20100   // N*(N+1)/2 unique (i<=j) pairs: S[(i,j)] == S[(j,i)]
#define NTP 20160  // NT rounded up to 64

// Workspace layout (float units).
#define WS_BASE   0
#define WS_H1     19200
#define WS_H2     38400
#define WS_HFULL  57600
#define WS_KHF    194952   // khfT [DM][NV] = 94400 floats (transposed!)
#define WS_VHF    289352
#define WS_B1     383752   // after k_SC: reused for C (softmax row consts)
#define WS_B2     478152
#define WS_SC1    572552
#define WS_SC2    732552
#define WS_ZT     1315464  // ZT bf16: 512*896 ushorts = 229,376 floats

// Output layout (floats)
#define OFF_H   18880000
#define OFF_HF  18899200
#define OFF_Q   18922800

typedef __attribute__((ext_vector_type(8))) short short8v;
typedef __attribute__((ext_vector_type(4))) float float4v;

__device__ __forceinline__ ushort f2bf(float f) {
  uint u = __float_as_uint(f);
  uint r = (u + 0x7fffu + ((u >> 16) & 1u)) >> 16;  // RNE
  return (ushort)r;
}
__device__ __forceinline__ uint packbf(float a, float b) {
  __hip_bfloat162 h2 = __float22bfloat162_rn(make_float2(a, b));
  union { __hip_bfloat162 h; uint u; } c;
  c.h = h2;
  return c.u;
}

// Packed upper-triangle index p (0..NT-1) -> (i,j), i<=j.
__device__ __forceinline__ int triOff(int i) {
  return i * 200 - ((i * (i - 1)) >> 1);
}
__device__ __forceinline__ void p2ij(int p, int& io, int& jo) {
  float s = sqrtf((float)(160801 - 8 * p));   // (2N+1)^2 - 8p
  int i = (int)((401.0f - s) * 0.5f);
  if (i < 0) i = 0;
  if (i > 199) i = 199;
  while (i > 0 && triOff(i) > p) --i;
  while (i < 199 && triOff(i + 1) <= p) ++i;
  io = i;
  jo = i + (p - triOff(i));
}

// ---------------------------------------------------------------------------
// A: iteration-invariant part of the GCN update
// ---------------------------------------------------------------------------
__global__ __launch_bounds__(256) void k_base(
    const float* __restrict__ x, const float* __restrict__ dmat,
    const float* __restrict__ label,
    const float* __restrict__ l0w, const float* __restrict__ l0b,
    const float* __restrict__ l1w, const float* __restrict__ l1b,
    const float* __restrict__ l2b, const float* __restrict__ l3b,
    const float* __restrict__ l4w, const float* __restrict__ l4b,
    const float* __restrict__ l5w, const float* __restrict__ l5b,
    float* __restrict__ base) {
  int i = blockIdx.x; int t = threadIdx.x;
  int g = i / MG;
  __shared__ float sv[256];
  __shared__ float sn2[9];
  float v = -1.0f;
  if (t < DEG) {
    int u = (t < i) ? t : t + 1;
    if (u / MG != g) v = dmat[i * DEG + t];
  }
  sv[t] = v;
  __syncthreads();
  for (int k2 = 2; k2 <= 256; k2 <<= 1) {
    for (int jj = k2 >> 1; jj > 0; jj >>= 1) {
      int ixj = t ^ jj;
      if (ixj > t) {
        float a = sv[t], b = sv[ixj];
        bool sw = ((t & k2) == 0) ? (a < b) : (a > b);
        if (sw) { sv[t] = b; sv[ixj] = a; }
      }
      __syncthreads();
    }
  }
  if (t == 0) {
    float tmp[9];
    for (int q = 0; q < 9; q++) tmp[q] = dmat[i * DEG + MG * g + q];
    for (int a2 = 1; a2 < 9; a2++) {
      float key = tmp[a2]; int b2 = a2 - 1;
      while (b2 >= 0 && tmp[b2] < key) { tmp[b2 + 1] = tmp[b2]; b2--; }
      tmp[b2 + 1] = key;
    }
    for (int q = 0; q < 9; q++) sn2[q] = tmp[q];
  }
  __syncthreads();
  if (t < HID) {
    float acc = l0b[t] + l1b[t] + l2b[t] + l3b[t] + l4b[t] + l5b[t];
    acc += x[i * 2 + 0] * l0w[t] + x[i * 2 + 1] * l0w[HID + t];
    for (int k = 0; k < KG; k++) acc += label[i * KG + k] * l1w[k * HID + t];
    for (int q = 0; q < AJR; q++) acc += sv[q] * l4w[q * HID + t];
    for (int q = 0; q < 9; q++) acc += sn2[q] * l5w[q * HID + t];
    base[i * HID + t] = acc;
  }
}

// ---------------------------------------------------------------------------
// B (v11): one GCN step, serial length quartered. 512 threads:
//   t<384: 4 groups x 96 threads, n1 partials over j-quarters;
//   384<=t<416: n2 (3 dd each). Then dd-matmul split 4 ways (24 dd each).
// ---------------------------------------------------------------------------
__global__ __launch_bounds__(512) void k_gcn4(
    const float* __restrict__ hin, const float* __restrict__ base,
    const float* __restrict__ w, const float* __restrict__ l2w,
    const float* __restrict__ l3w, float* __restrict__ hout) {
  int i = blockIdx.x; int t = threadIdx.x;
  int g = i / MG;
  __shared__ float pJ[4][HID], wJ[4][HID];
  __shared__ float n1s[HID], n2s[HID];
  __shared__ float m[4][HID];
  if (t < 384) {
    int q = t / HID;
    int c = t - q * HID;
    int j0 = q * 50, j1 = (q == 3) ? DEG : (j0 + 50);
    float acc = 0.f, ws = 0.f;
    for (int j = j0; j < j1; j++) {
      int u = (j < i) ? j : j + 1;
      if (u / MG != g) {
        float wj = w[i * DEG + j];
        acc += wj * hin[u * HID + c];
        ws += wj;
      }
    }
    pJ[q][c] = acc; wJ[q][c] = ws;
  } else if (t < 416) {
#pragma unroll
    for (int q2 = 0; q2 < 3; q2++) {
      int dd = (t - 384) * 3 + q2;
      float acc = 0.f, ws = 0.f;
      for (int u = MG * g; u < MG * g + MG; u++) {
        if (u == i) continue;
        int j = (u < i) ? u : u - 1;
        float wj = w[i * DEG + j];
        acc += wj * hin[u * HID + dd];
        ws += wj;
      }
      n2s[dd] = acc / ws;
    }
  }
  __syncthreads();
  if (t < HID)
    n1s[t] = (pJ[0][t] + pJ[1][t] + pJ[2][t] + pJ[3][t]) /
             (wJ[0][t] + wJ[1][t] + wJ[2][t] + wJ[3][t]);
  __syncthreads();
  if (t < 384) {
    int q = t / HID, c = t - q * HID;
    int d0 = q * 24;
    float acc = 0.f;
    for (int dd = d0; dd < d0 + 24; dd++)
      acc += n1s[dd] * l2w[dd * HID + c] + n2s[dd] * l3w[dd * HID + c];
    m[q][c] = acc;
  }
  __syncthreads();
  if (t < HID)
    hout[i * HID + t] =
        fmaxf(base[i * HID + t] + m[0][t] + m[1][t] + m[2][t] + m[3][t], 0.f);
}

// ---------------------------------------------------------------------------
// C1: h_full assembly (+ h, h_full outputs)
// ---------------------------------------------------------------------------
__global__ __launch_bounds__(128) void k_hfull(
    const float* __restrict__ h, const float* __restrict__ x,
    const float* __restrict__ label, const int* __restrict__ remain_step,
    float* __restrict__ hfull, float* __restrict__ out_h,
    float* __restrict__ out_hf) {
  int i = blockIdx.x; int t = threadIdx.x;
  if (t < HD) {
    float v;
    if (t < HID) {
      int p = *remain_step;
      int t2 = t & ~1;
      float div = expf(-(float)t2 * (logf(10000.f) / (float)HID));
      float ang = (float)p * div;
      float pe = (t & 1) ? cosf(ang) : sinf(ang);
      float hv = h[i * HID + t];
      out_h[i * HID + t] = hv;
      v = hv + pe;
    } else if (t < HID + 2) {
      v = x[i * 2 + (t - HID)];
    } else {
      v = label[i * KG + (t - HID - 2)];
    }
    hfull[i * HD + t] = v;
    out_hf[i * HD + t] = v;
  }
}

// ---------------------------------------------------------------------------
// D (v11): fused k_wsum + k_kv + k_B + k_gmean (gr computed inline).
// Grid (NV, 2): column halves.
// ---------------------------------------------------------------------------
__global__ __launch_bounds__(256) void k_kvB(
    const float* __restrict__ hfull,
    const float* __restrict__ w0, const float* __restrict__ b0v,
    const float* __restrict__ w1, const float* __restrict__ b1v,
    float* __restrict__ khfT, float* __restrict__ vhf,
    float* __restrict__ B1, float* __restrict__ B2) {
  int i = blockIdx.x; int t = threadIdx.x; int g = i / MG;
  int half = blockIdx.y;
  __shared__ float hr[HD], gr[HD];
  if (t < HD) {
    hr[t] = hfull[i * HD + t];
    float s = 0.f;
    for (int q = 0; q < MG; q++) s += hfull[(g * MG + q) * HD + t];
    gr[t] = s * 0.1f;
  }
  __syncthreads();
  for (int c = half * 236 + t; c < 236 + half * 236; c += 256) {
    const float* w0c = w0 + c;
    const float* w1c = w1 + c;
    float d0 = 0.f, d1 = 0.f, d2 = 0.f, d3 = 0.f;
    float g2 = 0.f, g3 = 0.f;
    float e0 = 0.f, e1 = 0.f, e2 = 0.f, e3 = 0.f;
    for (int dd = 0; dd < HD; dd++) {
      float hv = hr[dd], gv = gr[dd];
      float a0 = w0c[dd * DM];
      float a1 = w0c[(HD + dd) * DM];
      float a2 = w0c[(2 * HD + dd) * DM];
      float a3 = w0c[(3 * HD + dd) * DM];
      d0 += hv * a0; d1 += hv * a1; d2 += hv * a2; d3 += hv * a3;
      g2 += gv * a2; g3 += gv * a3;
      e0 += hv * w1c[dd * DM];
      e1 += hv * w1c[(HD + dd) * DM];
      e2 += hv * w1c[(2 * HD + dd) * DM];
      e3 += hv * w1c[(3 * HD + dd) * DM];
    }
    float b0c = b0v[c];
    khfT[c * NV + i] = b0c + d0 + d1 + d2 + d3;
    vhf[i * DM + c] = b1v[c] + e0 + e1 + e2 + e3;
    B1[i * DM + c] = d0 + g2;
    B2[i * DM + c] = b0c + d1 + g3;
  }
}

// D4 (v11): score components; grid (NV, 4) -- p-range quarters.
__global__ __launch_bounds__(256) void k_SC(
    const float* __restrict__ B1, const float* __restrict__ B2,
    const float* __restrict__ khfT, float* __restrict__ SC1,
    float* __restrict__ SC2) {
  int i = blockIdx.x; int t = threadIdx.x;
  int qtr = blockIdx.y;
  const float scl = 1.4426950408889634f / sqrtf((float)HD);
  __shared__ float b1r[DM], b2r[DM];
  for (int c = t; c < DM; c += 256) { b1r[c] = B1[i * DM + c]; b2r[c] = B2[i * DM + c]; }
  __syncthreads();
  for (int p = qtr * 200 + t; p < qtr * 200 + 200; p += 256) {
    int h = p / NV, k = p - h * NV;
    float s1a = 0.f, s2a = 0.f;
    const float* kc = khfT + (size_t)h * HD * NV + k;
    const float* b1h = b1r + h * HD;
    const float* b2h = b2r + h * HD;
    for (int dd = 0; dd < HD; dd++) {
      float kv = kc[dd * NV];
      s1a += b1h[dd] * kv;
      s2a += b2h[dd] * kv;
    }
    SC1[h * NN + i * NV + k] = s1a * scl;
    SC2[h * NN + i * NV + k] = s2a * scl;
  }
}

// D5 (v11): softmax row constants; grid (NV, NH*2) -- j-range halves.
__global__ __launch_bounds__(256) void k_ml(
    const float* __restrict__ SC1, const float* __restrict__ SC2,
    float* __restrict__ C) {
  int i = blockIdx.x;
  int h = blockIdx.y >> 1, jh = blockIdx.y & 1;
  int t = threadIdx.x;
  __shared__ float s1s[224];
  for (int k = t; k < 224; k += 256)
    s1s[k] = (k < NV) ? SC1[h * NN + i * NV + k] : -1e30f;
  __syncthreads();
  int l = t & 31;
  int g = t >> 5;
  const float* s2b = SC2 + h * NN;
  int it0 = jh ? 13 : 0, it1 = jh ? 25 : 13;
  for (int it = it0; it < it1; ++it) {
    int j = it * 8 + g;
    const float* row = s2b + j * NV;
    float v[7];
#pragma unroll
    for (int e = 0; e < 7; ++e) {
      int k = l + 32 * e;
      v[e] = (k < NV) ? (s1s[k] + row[k]) : -1e30f;
    }
    float m = v[0];
#pragma unroll
    for (int e = 1; e < 7; ++e) m = fmaxf(m, v[e]);
#pragma unroll
    for (int off = 16; off > 0; off >>= 1) m = fmaxf(m, __shfl_xor(m, off, 32));
    float s = 0.f;
#pragma unroll
    for (int e = 0; e < 7; ++e) s += exp2f(v[e] - m);
#pragma unroll
    for (int off = 16; off > 0; off >>= 1) s += __shfl_xor(s, off, 32);
    if (l == 0) C[h * NN + i * NV + j] = m + log2f(s);
  }
}

// ---------------------------------------------------------------------------
// E: merged k_Z + k_ZT. Writes bf16 directly into transposed zero-padded
// ZT[c][h*224+k] (512x896). Grid (224, NH).
// ---------------------------------------------------------------------------
__global__ __launch_bounds__(256) void k_ZZT(
    const float* __restrict__ vhf, const float* __restrict__ w3,
    ushort* __restrict__ ZT) {
  int k = blockIdx.x, h = blockIdx.y;
  int t = threadIdx.x;
  __shared__ float vr[HD];
  if (k < NV && t < HD) vr[t] = vhf[k * DM + h * HD + t];
  __syncthreads();
  for (int c = t; c < 512; c += 256) {
    float a = 0.f;
    if (k < NV && c < DM) {
      for (int d = 0; d < HD; ++d) a += vr[d] * w3[(h * HD + d) * DM + c];
    }
    ZT[(size_t)c * 896 + h * 224 + k] = f2bf(a);
  }
}

// ---------------------------------------------------------------------------
// F (v12 = v10's proven kernel, 112.7 us at 32.6% occupancy, measured twice):
// fused attention+output GEMM over UNIQUE row pairs. 64 packed rows x 128
// cols, grid (4, 315), 52 VGPR / 10 KB LDS. Established across v2/v3/v7/v11:
// deviating from this shape loses occupancy and regresses. Mirror write.
// ---------------------------------------------------------------------------
__global__ __launch_bounds__(256) void k_sfusedT2(
    const float* __restrict__ SC1, const float* __restrict__ SC2,
    const float* __restrict__ C, const ushort* __restrict__ ZT,
    const float* __restrict__ b3, float* __restrict__ outS) {
  int t = threadIdx.x;
  int c0 = blockIdx.x * 128, p0 = blockIdx.y * 64;
  int lane = t & 63, wm = t >> 6;
  int frow = lane & 15, quad = lane >> 4;
  __shared__ __align__(16) ushort Bs[128 * 40];
  int p = p0 + wm * 16 + frow;
  bool bval = (p < NT);
  int iA = 0, jA = 0;
  if (bval) p2ij(p, iA, jA);
  int iN = iA * NV, jN = jA * NV;
  float4v acc[8];
#pragma unroll
  for (int n = 0; n < 8; ++n) acc[n] = (float4v)(0.f);
  int rB = t >> 1, khB = (t & 1) * 16;

  for (int h = 0; h < NH; ++h) {
    int hb = h * NN;
    const float* s1h = SC1 + hb;
    const float* s2h = SC2 + hb;
    float ci = bval ? C[hb + iN + jA] : 0.f;
    float cj = bval ? C[hb + jN + iA] : 0.f;
    for (int ks = 0; ks < 7; ++ks) {
      int kb = ks * 32 + quad * 8;
      bool kvalid = (kb + 7 < NV);
      union { uint4 q; short8v v; } af;
      if (bval && kvalid) {
        const float* q1i = s1h + iN + kb;
        const float* q2i = s2h + iN + kb;
        const float* q1j = s1h + jN + kb;
        const float* q2j = s2h + jN + kb;
        float4 a0 = *(const float4*)q1i,   a0b = *(const float4*)(q1i + 4);
        float4 b0 = *(const float4*)q2j,   b0b = *(const float4*)(q2j + 4);
        float4 d0 = *(const float4*)q1j,   d0b = *(const float4*)(q1j + 4);
        float4 e0 = *(const float4*)q2i,   e0b = *(const float4*)(q2i + 4);
        float p0_ = exp2f(a0.x + b0.x - ci) + exp2f(d0.x + e0.x - cj);
        float p1_ = exp2f(a0.y + b0.y - ci) + exp2f(d0.y + e0.y - cj);
        float p2_ = exp2f(a0.z + b0.z - ci) + exp2f(d0.z + e0.z - cj);
        float p3_ = exp2f(a0.w + b0.w - ci) + exp2f(d0.w + e0.w - cj);
        float p4_ = exp2f(a0b.x + b0b.x - ci) + exp2f(d0b.x + e0b.x - cj);
        float p5_ = exp2f(a0b.y + b0b.y - ci) + exp2f(d0b.y + e0b.y - cj);
        float p6_ = exp2f(a0b.z + b0b.z - ci) + exp2f(d0b.z + e0b.z - cj);
        float p7_ = exp2f(a0b.w + b0b.w - ci) + exp2f(d0b.w + e0b.w - cj);
        af.q.x = packbf(p0_, p1_);
        af.q.y = packbf(p2_, p3_);
        af.q.z = packbf(p4_, p5_);
        af.q.w = packbf(p6_, p7_);
      } else {
        af.q = make_uint4(0, 0, 0, 0);
      }
      const uint4* wp = (const uint4*)(ZT + (size_t)(c0 + rB) * 896 +
                                       h * 224 + ks * 32 + khB);
      uint4 bq0 = wp[0], bq1 = wp[1];
      __syncthreads();
      *(uint4*)&Bs[rB * 40 + khB] = bq0;
      *(uint4*)&Bs[rB * 40 + khB + 8] = bq1;
      __syncthreads();
#pragma unroll
      for (int n = 0; n < 8; ++n) {
        short8v bf = *(const short8v*)&Bs[(n * 16 + frow) * 40 + quad * 8];
        acc[n] = __builtin_amdgcn_mfma_f32_16x16x32_bf16(af.v, bf, acc[n],
                                                         0, 0, 0);
      }
    }
  }
  int ie[4], je[4];
#pragma unroll
  for (int r2 = 0; r2 < 4; ++r2) {
    int pe = p0 + wm * 16 + quad * 4 + r2;
    if (pe < NT) {
      p2ij(pe, ie[r2], je[r2]);
    } else {
      ie[r2] = -1; je[r2] = 0;
    }
  }
#pragma unroll
  for (int n = 0; n < 8; ++n) {
    int c = c0 + n * 16 + frow;
    if (c >= DM) continue;
    float bb = 2.0f * b3[c];
#pragma unroll
    for (int r2 = 0; r2 < 4; ++r2) {
      int ii = ie[r2];
      if (ii < 0) continue;
      int jj = je[r2];
      float v = acc[n][r2] + bb;
      outS[(size_t)(ii * NV + jj) * DM + c] = v;
      if (ii != jj) outS[(size_t)(jj * NV + ii) * DM + c] = v;
    }
  }
}

// ---------------------------------------------------------------------------
// G: Q_sa = relu(S@v1+b1)@v2 + b2 over unique rows; 32 rows/block,
// 59-col chunks, conflict-free padded LDS. Mirror write.
// ---------------------------------------------------------------------------
__global__ __launch_bounds__(256) void k_qsaT2(
    const float* __restrict__ S, const float* __restrict__ v1w,
    const float* __restrict__ v1b, const float* __restrict__ v2w,
    const float* __restrict__ v2b, float* __restrict__ outQ) {
  __shared__ float Ss[32][61];
  __shared__ float V1s[59][48];
  __shared__ float Ts[32][49];
  __shared__ int rowI[32], rowJ[32], rowOfs[32];
  int t = threadIdx.x;
  int p0b = blockIdx.x * 32;
  if (t < 32) {
    int p = p0b + t;
    if (p < NT) {
      int ii, jj; p2ij(p, ii, jj);
      rowI[t] = ii; rowJ[t] = jj; rowOfs[t] = ii * NV + jj;
    } else {
      rowI[t] = -1; rowJ[t] = 0; rowOfs[t] = 0;
    }
  }
  int ty2 = (t >> 4) * 2;     // rows ty2, ty2+1
  int tx3 = (t & 15) * 3;     // q outputs tx3..tx3+2
  float a00 = 0.f, a01 = 0.f, a02 = 0.f, a10 = 0.f, a11 = 0.f, a12 = 0.f;
  for (int k0 = 0; k0 < DM; k0 += 59) {
    __syncthreads();
    for (int e = t; e < 32 * 59; e += 256) {
      int r = e / 59, cc = e - r * 59;
      Ss[r][cc] = S[(size_t)rowOfs[r] * DM + k0 + cc];
    }
    for (int e = t; e < 59 * 48; e += 256) {
      int kk = e / 48, cc = e - kk * 48;
      V1s[kk][cc] = v1w[(size_t)(k0 + kk) * 48 + cc];
    }
    __syncthreads();
    for (int kk = 0; kk < 59; ++kk) {
      float s0 = Ss[ty2][kk], s1 = Ss[ty2 + 1][kk];
      float w0_ = V1s[kk][tx3], w1_ = V1s[kk][tx3 + 1], w2_ = V1s[kk][tx3 + 2];
      a00 += s0 * w0_; a01 += s0 * w1_; a02 += s0 * w2_;
      a10 += s1 * w0_; a11 += s1 * w1_; a12 += s1 * w2_;
    }
  }
  float b0 = v1b[tx3], b1 = v1b[tx3 + 1], b2 = v1b[tx3 + 2];
  Ts[ty2][tx3] = fmaxf(a00 + b0, 0.f);
  Ts[ty2][tx3 + 1] = fmaxf(a01 + b1, 0.f);
  Ts[ty2][tx3 + 2] = fmaxf(a02 + b2, 0.f);
  Ts[ty2 + 1][tx3] = fmaxf(a10 + b0, 0.f);
  Ts[ty2 + 1][tx3 + 1] = fmaxf(a11 + b1, 0.f);
  Ts[ty2 + 1][tx3 + 2] = fmaxf(a12 + b2, 0.f);
  __syncthreads();
  if (t < 32 && rowI[t] >= 0) {
    float q = v2b[0];
    for (int c = 0; c < 48; c++) q += Ts[t][c] * v2w[c];
    int ii = rowI[t], jj = rowJ[t];
    outQ[ii * NV + jj] = q;
    if (ii != jj) outQ[jj * NV + ii] = q;
  }
}

// ---------------------------------------------------------------------------
extern "C" void kernel_launch(void* const* d_in, const int* in_sizes, int n_in,
                              void* d_out, int out_size, void* d_ws,
                              size_t ws_size, hipStream_t stream) {
  const float* x = (const float*)d_in[0];
  const float* label = (const float*)d_in[1];
  const float* h0 = (const float*)d_in[2];
  const float* w = (const float*)d_in[3];
  const float* dmat = (const float*)d_in[4];
  const float* l0w = (const float*)d_in[5];
  const float* l0b = (const float*)d_in[6];
  const float* l1w = (const float*)d_in[7];
  const float* l1b = (const float*)d_in[8];
  const float* l2w = (const float*)d_in[9];
  const float* l2b = (const float*)d_in[10];
  const float* l3w = (const float*)d_in[11];
  const float* l3b = (const float*)d_in[12];
  const float* l4w = (const float*)d_in[13];
  const float* l4b = (const float*)d_in[14];
  const float* l5w = (const float*)d_in[15];
  const float* l5b = (const float*)d_in[16];
  const float* w0 = (const float*)d_in[17];
  const float* b0v = (const float*)d_in[18];
  const float* w1 = (const float*)d_in[19];
  const float* b1v = (const float*)d_in[20];
  const float* w3 = (const float*)d_in[21];
  const float* b3 = (const float*)d_in[22];
  const float* v1w = (const float*)d_in[23];
  const float* v1b = (const float*)d_in[24];
  const float* v2w = (const float*)d_in[25];
  const float* v2b = (const float*)d_in[26];
  const int* remain_step = (const int*)d_in[29];

  float* ws = (float*)d_ws;
  float* base = ws + WS_BASE;
  float* h1 = ws + WS_H1;
  float* h2 = ws + WS_H2;
  float* hfull = ws + WS_HFULL;
  float* khfT = ws + WS_KHF;
  float* vhf = ws + WS_VHF;
  float* B1 = ws + WS_B1;
  float* B2 = ws + WS_B2;
  float* SC1 = ws + WS_SC1;
  float* SC2 = ws + WS_SC2;
  ushort* ZT = (ushort*)(ws + WS_ZT);
  float* C = ws + WS_B1;  // reuses B1/B2 slots after k_SC

  float* outS = (float*)d_out;
  float* outH = outS + OFF_H;
  float* outHF = outS + OFF_HF;
  float* outQ = outS + OFF_Q;

  k_base<<<NV, 256, 0, stream>>>(x, dmat, label, l0w, l0b, l1w, l1b, l2b, l3b,
                                 l4w, l4b, l5w, l5b, base);
  k_gcn4<<<NV, 512, 0, stream>>>(h0, base, w, l2w, l3w, h1);
  k_gcn4<<<NV, 512, 0, stream>>>(h1, base, w, l2w, l3w, h2);
  k_hfull<<<NV, 128, 0, stream>>>(h2, x, label, remain_step, hfull, outH, outHF);
  k_kvB<<<dim3(NV, 2), 256, 0, stream>>>(hfull, w0, b0v, w1, b1v, khfT, vhf,
                                         B1, B2);
  k_ZZT<<<dim3(224, NH), 256, 0, stream>>>(vhf, w3, ZT);
  k_SC<<<dim3(NV, 4), 256, 0, stream>>>(B1, B2, khfT, SC1, SC2);
  k_ml<<<dim3(NV, NH * 2), 256, 0, stream>>>(SC1, SC2, C);
  k_sfusedT2<<<dim3(4, NTP / 64), 256, 0, stream>>>(SC1, SC2, C, ZT, b3, outS);
  k_qsaT2<<<(NT + 31) / 32, 256, 0, stream>>>(outS, v1w, v1b, v2w, v2b, outQ);
}

// Round 12
// 439.464 us; speedup vs baseline: 1.2167x; 1.0455x over previous
//
#include <hip/hip_runtime.h>
#include <hip/hip_bf16.h>
#include <math.h>

typedef unsigned short ushort;
typedef unsigned int uint;

// Sizes (fixed by the reference problem)
#define NV 200     // N nodes
#define DEG 199
#define HID 96
#define KG 20      // groups / one-hot width
#define MG 10      // group size
#define AJR 30
#define NH 4
#define HD 118     // HID + 2 + K
#define DM 472     // NH*HD
#define NN 40000   // N*N
#define NT 20100   // N*(N+1)/2 unique (i<=j) pairs: S[(i,j)] == S[(j,i)]
#define NTP 20160  // NT rounded up to 64

// Workspace layout (float units).
#define WS_BASE   0
#define WS_H1     19200
#define WS_H2     38400
#define WS_HFULL  57600
#define WS_KHF    194952   // khfT [DM][NV] = 94400 floats (transposed!)
#define WS_VHF    289352
#define WS_B1     383752   // after k_SC: reused for C (softmax row consts)
#define WS_B2     478152
#define WS_SC1    572552
#define WS_SC2    732552
#define WS_ZT     1315464  // ZT bf16: 512*896 ushorts = 229,376 floats

// Output layout (floats)
#define OFF_H   18880000
#define OFF_HF  18899200
#define OFF_Q   18922800

typedef __attribute__((ext_vector_type(8))) short short8v;
typedef __attribute__((ext_vector_type(4))) float float4v;

__device__ __forceinline__ ushort f2bf(float f) {
  uint u = __float_as_uint(f);
  uint r = (u + 0x7fffu + ((u >> 16) & 1u)) >> 16;  // RNE
  return (ushort)r;
}
__device__ __forceinline__ uint packbf(float a, float b) {
  __hip_bfloat162 h2 = __float22bfloat162_rn(make_float2(a, b));
  union { __hip_bfloat162 h; uint u; } c;
  c.h = h2;
  return c.u;
}

// Packed upper-triangle index p (0..NT-1) -> (i,j), i<=j.
__device__ __forceinline__ int triOff(int i) {
  return i * 200 - ((i * (i - 1)) >> 1);
}
__device__ __forceinline__ void p2ij(int p, int& io, int& jo) {
  float s = sqrtf((float)(160801 - 8 * p));   // (2N+1)^2 - 8p
  int i = (int)((401.0f - s) * 0.5f);
  if (i < 0) i = 0;
  if (i > 199) i = 199;
  while (i > 0 && triOff(i) > p) --i;
  while (i < 199 && triOff(i + 1) <= p) ++i;
  io = i;
  jo = i + (p - triOff(i));
}

// ---------------------------------------------------------------------------
// A+B1 (v13): fused k_base + GCN step 1. 512 threads, grid NV.
// Phase 1 (t<256 active, barriers uniform across all 512): bitonic top-30 +
// group top-9 + base accumulation (kept in LDS bb[] AND written to global for
// step 2). Phase 2: k_gcn4's quartered GCN step on h0 -> h1.
// ---------------------------------------------------------------------------
__global__ __launch_bounds__(512) void k_bgcn(
    const float* __restrict__ x, const float* __restrict__ dmat,
    const float* __restrict__ label,
    const float* __restrict__ l0w, const float* __restrict__ l0b,
    const float* __restrict__ l1w, const float* __restrict__ l1b,
    const float* __restrict__ l2b, const float* __restrict__ l3b,
    const float* __restrict__ l4w, const float* __restrict__ l4b,
    const float* __restrict__ l5w, const float* __restrict__ l5b,
    const float* __restrict__ hin, const float* __restrict__ w,
    const float* __restrict__ l2w, const float* __restrict__ l3w,
    float* __restrict__ base, float* __restrict__ hout) {
  int i = blockIdx.x; int t = threadIdx.x;
  int g = i / MG;
  __shared__ float sv[256];
  __shared__ float sn2[9];
  __shared__ float bb[HID];
  __shared__ float pJ[4][HID], wJ[4][HID];
  __shared__ float n1s[HID], n2s[HID];
  __shared__ float m[4][HID];
  // ---- base phase ----
  if (t < 256) {
    float v = -1.0f;
    if (t < DEG) {
      int u = (t < i) ? t : t + 1;
      if (u / MG != g) v = dmat[i * DEG + t];
    }
    sv[t] = v;
  }
  __syncthreads();
  for (int k2 = 2; k2 <= 256; k2 <<= 1) {
    for (int jj = k2 >> 1; jj > 0; jj >>= 1) {
      if (t < 256) {
        int ixj = t ^ jj;
        if (ixj > t) {
          float a = sv[t], b = sv[ixj];
          bool sw = ((t & k2) == 0) ? (a < b) : (a > b);
          if (sw) { sv[t] = b; sv[ixj] = a; }
        }
      }
      __syncthreads();
    }
  }
  if (t == 0) {
    float tmp[9];
    for (int q = 0; q < 9; q++) tmp[q] = dmat[i * DEG + MG * g + q];
    for (int a2 = 1; a2 < 9; a2++) {
      float key = tmp[a2]; int b2 = a2 - 1;
      while (b2 >= 0 && tmp[b2] < key) { tmp[b2 + 1] = tmp[b2]; b2--; }
      tmp[b2 + 1] = key;
    }
    for (int q = 0; q < 9; q++) sn2[q] = tmp[q];
  }
  __syncthreads();
  if (t < HID) {
    float acc = l0b[t] + l1b[t] + l2b[t] + l3b[t] + l4b[t] + l5b[t];
    acc += x[i * 2 + 0] * l0w[t] + x[i * 2 + 1] * l0w[HID + t];
    for (int k = 0; k < KG; k++) acc += label[i * KG + k] * l1w[k * HID + t];
    for (int q = 0; q < AJR; q++) acc += sv[q] * l4w[q * HID + t];
    for (int q = 0; q < 9; q++) acc += sn2[q] * l5w[q * HID + t];
    bb[t] = acc;
    base[i * HID + t] = acc;
  }
  // ---- GCN step 1 (h0 -> h1) ----
  if (t < 384) {
    int q = t / HID;
    int c = t - q * HID;
    int j0 = q * 50, j1 = (q == 3) ? DEG : (j0 + 50);
    float acc = 0.f, ws = 0.f;
    for (int j = j0; j < j1; j++) {
      int u = (j < i) ? j : j + 1;
      if (u / MG != g) {
        float wj = w[i * DEG + j];
        acc += wj * hin[u * HID + c];
        ws += wj;
      }
    }
    pJ[q][c] = acc; wJ[q][c] = ws;
  } else if (t < 416) {
#pragma unroll
    for (int q2 = 0; q2 < 3; q2++) {
      int dd = (t - 384) * 3 + q2;
      float acc = 0.f, ws = 0.f;
      for (int u = MG * g; u < MG * g + MG; u++) {
        if (u == i) continue;
        int j = (u < i) ? u : u - 1;
        float wj = w[i * DEG + j];
        acc += wj * hin[u * HID + dd];
        ws += wj;
      }
      n2s[dd] = acc / ws;
    }
  }
  __syncthreads();
  if (t < HID)
    n1s[t] = (pJ[0][t] + pJ[1][t] + pJ[2][t] + pJ[3][t]) /
             (wJ[0][t] + wJ[1][t] + wJ[2][t] + wJ[3][t]);
  __syncthreads();
  if (t < 384) {
    int q = t / HID, c = t - q * HID;
    int d0 = q * 24;
    float acc = 0.f;
    for (int dd = d0; dd < d0 + 24; dd++)
      acc += n1s[dd] * l2w[dd * HID + c] + n2s[dd] * l3w[dd * HID + c];
    m[q][c] = acc;
  }
  __syncthreads();
  if (t < HID)
    hout[i * HID + t] =
        fmaxf(bb[t] + m[0][t] + m[1][t] + m[2][t] + m[3][t], 0.f);
}

// ---------------------------------------------------------------------------
// B2+C1 (v13): fused GCN step 2 + h_full assembly. 512 threads, grid NV.
// ---------------------------------------------------------------------------
__global__ __launch_bounds__(512) void k_gcnhf(
    const float* __restrict__ hin, const float* __restrict__ base,
    const float* __restrict__ w, const float* __restrict__ l2w,
    const float* __restrict__ l3w, const float* __restrict__ x,
    const float* __restrict__ label, const int* __restrict__ remain_step,
    float* __restrict__ hfull, float* __restrict__ out_h,
    float* __restrict__ out_hf) {
  int i = blockIdx.x; int t = threadIdx.x;
  int g = i / MG;
  __shared__ float pJ[4][HID], wJ[4][HID];
  __shared__ float n1s[HID], n2s[HID];
  __shared__ float m[4][HID];
  if (t < 384) {
    int q = t / HID;
    int c = t - q * HID;
    int j0 = q * 50, j1 = (q == 3) ? DEG : (j0 + 50);
    float acc = 0.f, ws = 0.f;
    for (int j = j0; j < j1; j++) {
      int u = (j < i) ? j : j + 1;
      if (u / MG != g) {
        float wj = w[i * DEG + j];
        acc += wj * hin[u * HID + c];
        ws += wj;
      }
    }
    pJ[q][c] = acc; wJ[q][c] = ws;
  } else if (t < 416) {
#pragma unroll
    for (int q2 = 0; q2 < 3; q2++) {
      int dd = (t - 384) * 3 + q2;
      float acc = 0.f, ws = 0.f;
      for (int u = MG * g; u < MG * g + MG; u++) {
        if (u == i) continue;
        int j = (u < i) ? u : u - 1;
        float wj = w[i * DEG + j];
        acc += wj * hin[u * HID + dd];
        ws += wj;
      }
      n2s[dd] = acc / ws;
    }
  }
  __syncthreads();
  if (t < HID)
    n1s[t] = (pJ[0][t] + pJ[1][t] + pJ[2][t] + pJ[3][t]) /
             (wJ[0][t] + wJ[1][t] + wJ[2][t] + wJ[3][t]);
  __syncthreads();
  if (t < 384) {
    int q = t / HID, c = t - q * HID;
    int d0 = q * 24;
    float acc = 0.f;
    for (int dd = d0; dd < d0 + 24; dd++)
      acc += n1s[dd] * l2w[dd * HID + c] + n2s[dd] * l3w[dd * HID + c];
    m[q][c] = acc;
  }
  __syncthreads();
  if (t < HID) {
    float hv =
        fmaxf(base[i * HID + t] + m[0][t] + m[1][t] + m[2][t] + m[3][t], 0.f);
    out_h[i * HID + t] = hv;
    int p = *remain_step;
    int t2 = t & ~1;
    float div = expf(-(float)t2 * (logf(10000.f) / (float)HID));
    float ang = (float)p * div;
    float pe = (t & 1) ? cosf(ang) : sinf(ang);
    float v = hv + pe;
    hfull[i * HD + t] = v;
    out_hf[i * HD + t] = v;
  } else if (t < HD) {
    float v = (t < HID + 2) ? x[i * 2 + (t - HID)]
                            : label[i * KG + (t - HID - 2)];
    hfull[i * HD + t] = v;
    out_hf[i * HD + t] = v;
  }
}

// ---------------------------------------------------------------------------
// D (v13): fused wsum+kv+B+gmean, TWO i-rows per block sharing every w0/w1
// load (L2 traffic 712 MB -> 178 MB). Grid (100, 4): i0=bx, i1=bx+100;
// quarter q covers cols [q*118, q*118+118). 128 threads.
// ---------------------------------------------------------------------------
__global__ __launch_bounds__(128) void k_kvB2(
    const float* __restrict__ hfull,
    const float* __restrict__ w0, const float* __restrict__ b0v,
    const float* __restrict__ w1, const float* __restrict__ b1v,
    float* __restrict__ khfT, float* __restrict__ vhf,
    float* __restrict__ B1, float* __restrict__ B2) {
  int i0 = blockIdx.x, i1 = blockIdx.x + 100;
  int q = blockIdx.y;
  int t = threadIdx.x;
  int g0 = i0 / MG, g1 = i1 / MG;
  __shared__ float hr0[HD], gr0[HD], hr1[HD], gr1[HD];
  if (t < HD) {
    hr0[t] = hfull[i0 * HD + t];
    hr1[t] = hfull[i1 * HD + t];
    float s0 = 0.f, s1 = 0.f;
    for (int u = 0; u < MG; u++) {
      s0 += hfull[(g0 * MG + u) * HD + t];
      s1 += hfull[(g1 * MG + u) * HD + t];
    }
    gr0[t] = s0 * 0.1f;
    gr1[t] = s1 * 0.1f;
  }
  __syncthreads();
  int c = q * 118 + t;
  if (t < 118) {
    const float* w0c = w0 + c;
    const float* w1c = w1 + c;
    float d0a = 0.f, d1a = 0.f, d2a = 0.f, d3a = 0.f;
    float g2a = 0.f, g3a = 0.f;
    float e0a = 0.f, e1a = 0.f, e2a = 0.f, e3a = 0.f;
    float d0b = 0.f, d1b = 0.f, d2b = 0.f, d3b = 0.f;
    float g2b = 0.f, g3b = 0.f;
    float e0b = 0.f, e1b = 0.f, e2b = 0.f, e3b = 0.f;
    for (int dd = 0; dd < HD; dd++) {
      float a0 = w0c[dd * DM];
      float a1 = w0c[(HD + dd) * DM];
      float a2 = w0c[(2 * HD + dd) * DM];
      float a3 = w0c[(3 * HD + dd) * DM];
      float b0 = w1c[dd * DM];
      float b1 = w1c[(HD + dd) * DM];
      float b2 = w1c[(2 * HD + dd) * DM];
      float b3 = w1c[(3 * HD + dd) * DM];
      float h0v = hr0[dd], g0v = gr0[dd];
      float h1v = hr1[dd], g1v = gr1[dd];
      d0a += h0v * a0; d1a += h0v * a1; d2a += h0v * a2; d3a += h0v * a3;
      g2a += g0v * a2; g3a += g0v * a3;
      e0a += h0v * b0; e1a += h0v * b1; e2a += h0v * b2; e3a += h0v * b3;
      d0b += h1v * a0; d1b += h1v * a1; d2b += h1v * a2; d3b += h1v * a3;
      g2b += g1v * a2; g3b += g1v * a3;
      e0b += h1v * b0; e1b += h1v * b1; e2b += h1v * b2; e3b += h1v * b3;
    }
    float b0c = b0v[c], b1c = b1v[c];
    khfT[c * NV + i0] = b0c + d0a + d1a + d2a + d3a;
    vhf[i0 * DM + c] = b1c + e0a + e1a + e2a + e3a;
    B1[i0 * DM + c] = d0a + g2a;
    B2[i0 * DM + c] = b0c + d1a + g3a;
    khfT[c * NV + i1] = b0c + d0b + d1b + d2b + d3b;
    vhf[i1 * DM + c] = b1c + e0b + e1b + e2b + e3b;
    B1[i1 * DM + c] = d0b + g2b;
    B2[i1 * DM + c] = b0c + d1b + g3b;
  }
}

// D4: score components; grid (NV, 4) -- p-range quarters.
__global__ __launch_bounds__(256) void k_SC(
    const float* __restrict__ B1, const float* __restrict__ B2,
    const float* __restrict__ khfT, float* __restrict__ SC1,
    float* __restrict__ SC2) {
  int i = blockIdx.x; int t = threadIdx.x;
  int qtr = blockIdx.y;
  const float scl = 1.4426950408889634f / sqrtf((float)HD);
  __shared__ float b1r[DM], b2r[DM];
  for (int c = t; c < DM; c += 256) { b1r[c] = B1[i * DM + c]; b2r[c] = B2[i * DM + c]; }
  __syncthreads();
  for (int p = qtr * 200 + t; p < qtr * 200 + 200; p += 256) {
    int h = p / NV, k = p - h * NV;
    float s1a = 0.f, s2a = 0.f;
    const float* kc = khfT + (size_t)h * HD * NV + k;
    const float* b1h = b1r + h * HD;
    const float* b2h = b2r + h * HD;
    for (int dd = 0; dd < HD; dd++) {
      float kv = kc[dd * NV];
      s1a += b1h[dd] * kv;
      s2a += b2h[dd] * kv;
    }
    SC1[h * NN + i * NV + k] = s1a * scl;
    SC2[h * NN + i * NV + k] = s2a * scl;
  }
}

// D5: softmax row constants; grid (NV, NH*2) -- j-range halves.
__global__ __launch_bounds__(256) void k_ml(
    const float* __restrict__ SC1, const float* __restrict__ SC2,
    float* __restrict__ C) {
  int i = blockIdx.x;
  int h = blockIdx.y >> 1, jh = blockIdx.y & 1;
  int t = threadIdx.x;
  __shared__ float s1s[224];
  for (int k = t; k < 224; k += 256)
    s1s[k] = (k < NV) ? SC1[h * NN + i * NV + k] : -1e30f;
  __syncthreads();
  int l = t & 31;
  int g = t >> 5;
  const float* s2b = SC2 + h * NN;
  int it0 = jh ? 13 : 0, it1 = jh ? 25 : 13;
  for (int it = it0; it < it1; ++it) {
    int j = it * 8 + g;
    const float* row = s2b + j * NV;
    float v[7];
#pragma unroll
    for (int e = 0; e < 7; ++e) {
      int k = l + 32 * e;
      v[e] = (k < NV) ? (s1s[k] + row[k]) : -1e30f;
    }
    float m = v[0];
#pragma unroll
    for (int e = 1; e < 7; ++e) m = fmaxf(m, v[e]);
#pragma unroll
    for (int off = 16; off > 0; off >>= 1) m = fmaxf(m, __shfl_xor(m, off, 32));
    float s = 0.f;
#pragma unroll
    for (int e = 0; e < 7; ++e) s += exp2f(v[e] - m);
#pragma unroll
    for (int off = 16; off > 0; off >>= 1) s += __shfl_xor(s, off, 32);
    if (l == 0) C[h * NN + i * NV + j] = m + log2f(s);
  }
}

// ---------------------------------------------------------------------------
// E (v13): merged Z+ZT with TWO k per block sharing every w3 load (traffic
// 200 MB -> 100 MB). Grid (112, NH); k0 = 2*bx. bf16 writes are adjacent.
// ---------------------------------------------------------------------------
__global__ __launch_bounds__(256) void k_ZZT2(
    const float* __restrict__ vhf, const float* __restrict__ w3,
    ushort* __restrict__ ZT) {
  int k0 = blockIdx.x * 2, h = blockIdx.y;
  int t = threadIdx.x;
  bool v0 = (k0 < NV), v1 = (k0 + 1 < NV);
  __shared__ float vr0[HD], vr1[HD];
  if (t < HD) {
    vr0[t] = v0 ? vhf[k0 * DM + h * HD + t] : 0.f;
    vr1[t] = v1 ? vhf[(k0 + 1) * DM + h * HD + t] : 0.f;
  }
  __syncthreads();
  for (int c = t; c < 512; c += 256) {
    float a0 = 0.f, a1 = 0.f;
    if (c < DM && v0) {
      for (int d = 0; d < HD; ++d) {
        float wv = w3[(h * HD + d) * DM + c];
        a0 += vr0[d] * wv;
        a1 += vr1[d] * wv;
      }
    }
    ushort* zp = ZT + (size_t)c * 896 + h * 224 + k0;
    zp[0] = f2bf(a0);
    zp[1] = f2bf(v1 ? a1 : 0.f);
  }
}

// ---------------------------------------------------------------------------
// F (certified fixed point, 112.7-113.0 us x3 runs): fused attention+output
// GEMM over UNIQUE row pairs. 64 packed rows x 128 cols, grid (4, 315),
// 52 VGPR / 10 KB LDS / 32.5% occupancy. Do not reshape (v2/v3/v7/v11 law).
// ---------------------------------------------------------------------------
__global__ __launch_bounds__(256) void k_sfusedT2(
    const float* __restrict__ SC1, const float* __restrict__ SC2,
    const float* __restrict__ C, const ushort* __restrict__ ZT,
    const float* __restrict__ b3, float* __restrict__ outS) {
  int t = threadIdx.x;
  int c0 = blockIdx.x * 128, p0 = blockIdx.y * 64;
  int lane = t & 63, wm = t >> 6;
  int frow = lane & 15, quad = lane >> 4;
  __shared__ __align__(16) ushort Bs[128 * 40];
  int p = p0 + wm * 16 + frow;
  bool bval = (p < NT);
  int iA = 0, jA = 0;
  if (bval) p2ij(p, iA, jA);
  int iN = iA * NV, jN = jA * NV;
  float4v acc[8];
#pragma unroll
  for (int n = 0; n < 8; ++n) acc[n] = (float4v)(0.f);
  int rB = t >> 1, khB = (t & 1) * 16;

  for (int h = 0; h < NH; ++h) {
    int hb = h * NN;
    const float* s1h = SC1 + hb;
    const float* s2h = SC2 + hb;
    float ci = bval ? C[hb + iN + jA] : 0.f;
    float cj = bval ? C[hb + jN + iA] : 0.f;
    for (int ks = 0; ks < 7; ++ks) {
      int kb = ks * 32 + quad * 8;
      bool kvalid = (kb + 7 < NV);
      union { uint4 q; short8v v; } af;
      if (bval && kvalid) {
        const float* q1i = s1h + iN + kb;
        const float* q2i = s2h + iN + kb;
        const float* q1j = s1h + jN + kb;
        const float* q2j = s2h + jN + kb;
        float4 a0 = *(const float4*)q1i,   a0b = *(const float4*)(q1i + 4);
        float4 b0 = *(const float4*)q2j,   b0b = *(const float4*)(q2j + 4);
        float4 d0 = *(const float4*)q1j,   d0b = *(const float4*)(q1j + 4);
        float4 e0 = *(const float4*)q2i,   e0b = *(const float4*)(q2i + 4);
        float p0_ = exp2f(a0.x + b0.x - ci) + exp2f(d0.x + e0.x - cj);
        float p1_ = exp2f(a0.y + b0.y - ci) + exp2f(d0.y + e0.y - cj);
        float p2_ = exp2f(a0.z + b0.z - ci) + exp2f(d0.z + e0.z - cj);
        float p3_ = exp2f(a0.w + b0.w - ci) + exp2f(d0.w + e0.w - cj);
        float p4_ = exp2f(a0b.x + b0b.x - ci) + exp2f(d0b.x + e0b.x - cj);
        float p5_ = exp2f(a0b.y + b0b.y - ci) + exp2f(d0b.y + e0b.y - cj);
        float p6_ = exp2f(a0b.z + b0b.z - ci) + exp2f(d0b.z + e0b.z - cj);
        float p7_ = exp2f(a0b.w + b0b.w - ci) + exp2f(d0b.w + e0b.w - cj);
        af.q.x = packbf(p0_, p1_);
        af.q.y = packbf(p2_, p3_);
        af.q.z = packbf(p4_, p5_);
        af.q.w = packbf(p6_, p7_);
      } else {
        af.q = make_uint4(0, 0, 0, 0);
      }
      const uint4* wp = (const uint4*)(ZT + (size_t)(c0 + rB) * 896 +
                                       h * 224 + ks * 32 + khB);
      uint4 bq0 = wp[0], bq1 = wp[1];
      __syncthreads();
      *(uint4*)&Bs[rB * 40 + khB] = bq0;
      *(uint4*)&Bs[rB * 40 + khB + 8] = bq1;
      __syncthreads();
#pragma unroll
      for (int n = 0; n < 8; ++n) {
        short8v bf = *(const short8v*)&Bs[(n * 16 + frow) * 40 + quad * 8];
        acc[n] = __builtin_amdgcn_mfma_f32_16x16x32_bf16(af.v, bf, acc[n],
                                                         0, 0, 0);
      }
    }
  }
  int ie[4], je[4];
#pragma unroll
  for (int r2 = 0; r2 < 4; ++r2) {
    int pe = p0 + wm * 16 + quad * 4 + r2;
    if (pe < NT) {
      p2ij(pe, ie[r2], je[r2]);
    } else {
      ie[r2] = -1; je[r2] = 0;
    }
  }
#pragma unroll
  for (int n = 0; n < 8; ++n) {
    int c = c0 + n * 16 + frow;
    if (c >= DM) continue;
    float bb = 2.0f * b3[c];
#pragma unroll
    for (int r2 = 0; r2 < 4; ++r2) {
      int ii = ie[r2];
      if (ii < 0) continue;
      int jj = je[r2];
      float v = acc[n][r2] + bb;
      outS[(size_t)(ii * NV + jj) * DM + c] = v;
      if (ii != jj) outS[(size_t)(jj * NV + ii) * DM + c] = v;
    }
  }
}

// ---------------------------------------------------------------------------
// G: Q_sa = relu(S@v1+b1)@v2 + b2 over unique rows; 32 rows/block,
// 59-col chunks, conflict-free padded LDS. Mirror write.
// ---------------------------------------------------------------------------
__global__ __launch_bounds__(256) void k_qsaT2(
    const float* __restrict__ S, const float* __restrict__ v1w,
    const float* __restrict__ v1b, const float* __restrict__ v2w,
    const float* __restrict__ v2b, float* __restrict__ outQ) {
  __shared__ float Ss[32][61];
  __shared__ float V1s[59][48];
  __shared__ float Ts[32][49];
  __shared__ int rowI[32], rowJ[32], rowOfs[32];
  int t = threadIdx.x;
  int p0b = blockIdx.x * 32;
  if (t < 32) {
    int p = p0b + t;
    if (p < NT) {
      int ii, jj; p2ij(p, ii, jj);
      rowI[t] = ii; rowJ[t] = jj; rowOfs[t] = ii * NV + jj;
    } else {
      rowI[t] = -1; rowJ[t] = 0; rowOfs[t] = 0;
    }
  }
  int ty2 = (t >> 4) * 2;     // rows ty2, ty2+1
  int tx3 = (t & 15) * 3;     // q outputs tx3..tx3+2
  float a00 = 0.f, a01 = 0.f, a02 = 0.f, a10 = 0.f, a11 = 0.f, a12 = 0.f;
  for (int k0 = 0; k0 < DM; k0 += 59) {
    __syncthreads();
    for (int e = t; e < 32 * 59; e += 256) {
      int r = e / 59, cc = e - r * 59;
      Ss[r][cc] = S[(size_t)rowOfs[r] * DM + k0 + cc];
    }
    for (int e = t; e < 59 * 48; e += 256) {
      int kk = e / 48, cc = e - kk * 48;
      V1s[kk][cc] = v1w[(size_t)(k0 + kk) * 48 + cc];
    }
    __syncthreads();
    for (int kk = 0; kk < 59; ++kk) {
      float s0 = Ss[ty2][kk], s1 = Ss[ty2 + 1][kk];
      float w0_ = V1s[kk][tx3], w1_ = V1s[kk][tx3 + 1], w2_ = V1s[kk][tx3 + 2];
      a00 += s0 * w0_; a01 += s0 * w1_; a02 += s0 * w2_;
      a10 += s1 * w0_; a11 += s1 * w1_; a12 += s1 * w2_;
    }
  }
  float b0 = v1b[tx3], b1 = v1b[tx3 + 1], b2 = v1b[tx3 + 2];
  Ts[ty2][tx3] = fmaxf(a00 + b0, 0.f);
  Ts[ty2][tx3 + 1] = fmaxf(a01 + b1, 0.f);
  Ts[ty2][tx3 + 2] = fmaxf(a02 + b2, 0.f);
  Ts[ty2 + 1][tx3] = fmaxf(a10 + b0, 0.f);
  Ts[ty2 + 1][tx3 + 1] = fmaxf(a11 + b1, 0.f);
  Ts[ty2 + 1][tx3 + 2] = fmaxf(a12 + b2, 0.f);
  __syncthreads();
  if (t < 32 && rowI[t] >= 0) {
    float q = v2b[0];
    for (int c = 0; c < 48; c++) q += Ts[t][c] * v2w[c];
    int ii = rowI[t], jj = rowJ[t];
    outQ[ii * NV + jj] = q;
    if (ii != jj) outQ[jj * NV + ii] = q;
  }
}

// ---------------------------------------------------------------------------
extern "C" void kernel_launch(void* const* d_in, const int* in_sizes, int n_in,
                              void* d_out, int out_size, void* d_ws,
                              size_t ws_size, hipStream_t stream) {
  const float* x = (const float*)d_in[0];
  const float* label = (const float*)d_in[1];
  const float* h0 = (const float*)d_in[2];
  const float* w = (const float*)d_in[3];
  const float* dmat = (const float*)d_in[4];
  const float* l0w = (const float*)d_in[5];
  const float* l0b = (const float*)d_in[6];
  const float* l1w = (const float*)d_in[7];
  const float* l1b = (const float*)d_in[8];
  const float* l2w = (const float*)d_in[9];
  const float* l2b = (const float*)d_in[10];
  const float* l3w = (const float*)d_in[11];
  const float* l3b = (const float*)d_in[12];
  const float* l4w = (const float*)d_in[13];
  const float* l4b = (const float*)d_in[14];
  const float* l5w = (const float*)d_in[15];
  const float* l5b = (const float*)d_in[16];
  const float* w0 = (const float*)d_in[17];
  const float* b0v = (const float*)d_in[18];
  const float* w1 = (const float*)d_in[19];
  const float* b1v = (const float*)d_in[20];
  const float* w3 = (const float*)d_in[21];
  const float* b3 = (const float*)d_in[22];
  const float* v1w = (const float*)d_in[23];
  const float* v1b = (const float*)d_in[24];
  const float* v2w = (const float*)d_in[25];
  const float* v2b = (const float*)d_in[26];
  const int* remain_step = (const int*)d_in[29];

  float* ws = (float*)d_ws;
  float* base = ws + WS_BASE;
  float* h1 = ws + WS_H1;
  float* hfull = ws + WS_HFULL;
  float* khfT = ws + WS_KHF;
  float* vhf = ws + WS_VHF;
  float* B1 = ws + WS_B1;
  float* B2 = ws + WS_B2;
  float* SC1 = ws + WS_SC1;
  float* SC2 = ws + WS_SC2;
  ushort* ZT = (ushort*)(ws + WS_ZT);
  float* C = ws + WS_B1;  // reuses B1/B2 slots after k_SC

  float* outS = (float*)d_out;
  float* outH = outS + OFF_H;
  float* outHF = outS + OFF_HF;
  float* outQ = outS + OFF_Q;

  k_bgcn<<<NV, 512, 0, stream>>>(x, dmat, label, l0w, l0b, l1w, l1b, l2b, l3b,
                                 l4w, l4b, l5w, l5b, h0, w, l2w, l3w, base, h1);
  k_gcnhf<<<NV, 512, 0, stream>>>(h1, base, w, l2w, l3w, x, label, remain_step,
                                  hfull, outH, outHF);
  k_kvB2<<<dim3(100, 4), 128, 0, stream>>>(hfull, w0, b0v, w1, b1v, khfT, vhf,
                                           B1, B2);
  k_ZZT2<<<dim3(112, NH), 256, 0, stream>>>(vhf, w3, ZT);
  k_SC<<<dim3(NV, 4), 256, 0, stream>>>(B1, B2, khfT, SC1, SC2);
  k_ml<<<dim3(NV, NH * 2), 256, 0, stream>>>(SC1, SC2, C);
  k_sfusedT2<<<dim3(4, NTP / 64), 256, 0, stream>>>(SC1, SC2, C, ZT, b3, outS);
  k_qsaT2<<<(NT + 31) / 32, 256, 0, stream>>>(outS, v1w, v1b, v2w, v2b, outQ);
}